// Round 12
// baseline (1847.222 us; speedup 1.0000x reference)
//
#include <hip/hip_runtime.h>

// BiLSTM-CRF on MI355X — round 12: R10 base (R11 cross-CU exchange reverted:
// XCD-crossing RTT ~2.7us/step killed it) + fp8(e4m3) compression of the
// slab (LDS 128->64 KB, b64 reads) and streamed (L2 128->64 KB/step) weight
// regions. Register region stays f16 dot2. Decode = v_cvt_pk_f32_fp8
// (__has_builtin-guarded; fallback = exact R10 f16 path).
//
// ws: X4 67108864 | WTH 1048576 | FT 786432 | WpH 12288 | H 16777216 |
//     WT8 262144  = 86.0 MB.
// Output (float32): d_out[0:16384] = paths (floats, -1 past length), [16384:16448] = best_score.

#define NB 64
#define NT 256
#define NKTAG 12
#define START_TAG 10
#define KK_SLAB 32
#define KK_REG 16
#define KK_STRM 8

#if defined(__has_builtin)
#if __has_builtin(__builtin_amdgcn_cvt_pk_f32_fp8) && __has_builtin(__builtin_amdgcn_cvt_pk_fp8_f32)
#define HAS_FP8 1
#endif
#endif
#ifndef HAS_FP8
#define HAS_FP8 0
#endif

typedef unsigned short u16;
typedef _Float16 half2v __attribute__((ext_vector_type(2)));
typedef _Float16 half8 __attribute__((ext_vector_type(8)));
typedef float f32x4 __attribute__((ext_vector_type(4)));
typedef float f32x2 __attribute__((ext_vector_type(2)));

__device__ __forceinline__ float b2f(u16 u) {
  union { unsigned int i; float f; } v; v.i = ((unsigned int)u) << 16; return v.f;
}
__device__ __forceinline__ u16 f2b(float f) {
  union { float f; unsigned int i; } v; v.f = f;
  unsigned int r = v.i + 0x7FFFu + ((v.i >> 16) & 1u);
  return (u16)(r >> 16);
}
__device__ __forceinline__ u16 f2h(float f) {
  union { _Float16 h; u16 u; } v; v.h = (_Float16)f; return v.u;
}
__device__ __forceinline__ unsigned int pkh(float x, float y) {
  return (unsigned int)f2h(x) | ((unsigned int)f2h(y) << 16);
}
__device__ __forceinline__ float fsig(float x) { return 1.0f / (1.0f + __expf(-x)); }
__device__ __forceinline__ float ftanh(float x) { return 2.0f / (1.0f + __expf(-2.0f * x)) - 1.0f; }

__device__ __forceinline__ float dot2h(unsigned int a, unsigned int b, float c) {
#if __has_builtin(__builtin_amdgcn_fdot2)
  union { unsigned int u; half2v h; } va, vb;
  va.u = a; vb.u = b;
  return __builtin_amdgcn_fdot2(va.h, vb.h, c, false);
#else
  float d;
  asm("v_dot2_f32_f16 %0, %1, %2, %3" : "=v"(d) : "v"(a), "v"(b), "v"(c));
  return d;
#endif
}

// ---------------------------------------------------------------- pack_whh (+WpH, +WT8)
__global__ __launch_bounds__(256) void pack_whh(const float* __restrict__ Whf,
                                                const float* __restrict__ Whb,
                                                const float* __restrict__ Wp,
                                                uint4* __restrict__ WT,
                                                unsigned int* __restrict__ WpH,
                                                uint2* __restrict__ WT8) {
  if (blockIdx.x == 256) {   // WpH: [12][256] packed f16 pairs of Wp[12][512]
    for (int it = 0; it < 12; ++it) {
      int idx = it * 256 + threadIdx.x;
      int k = idx >> 8, cc = idx & 255;
      WpH[idx] = pkh(Wp[(size_t)k * 512 + 2 * cc], Wp[(size_t)k * 512 + 2 * cc + 1]);
    }
    return;
  }
  if (blockIdx.x == 257) {   // WT8: fp8 for slab kk 0..31 (q<32) + stream kk 96..127
#if HAS_FP8
    for (int it = 0; it < 128; ++it) {
      int idx = it * 256 + threadIdx.x;       // [d][q][j], 2*64*256
      int d = idx >> 14;
      int rem = idx & 16383;
      int q = rem >> 8, j = rem & 255;
      int kk = (q < 32) ? q : (q + 64);
      const float* W = d ? Whb : Whf;
      int k0 = kk * 2;
      int d0 = 0, d1 = 0;
      d0 = __builtin_amdgcn_cvt_pk_fp8_f32(W[(size_t)j * 256 + k0],
                                           W[(size_t)(j + 256) * 256 + k0], d0, false);
      d0 = __builtin_amdgcn_cvt_pk_fp8_f32(W[(size_t)(j + 512) * 256 + k0],
                                           W[(size_t)(j + 768) * 256 + k0], d0, true);
      d1 = __builtin_amdgcn_cvt_pk_fp8_f32(W[(size_t)j * 256 + k0 + 1],
                                           W[(size_t)(j + 256) * 256 + k0 + 1], d1, false);
      d1 = __builtin_amdgcn_cvt_pk_fp8_f32(W[(size_t)(j + 512) * 256 + k0 + 1],
                                           W[(size_t)(j + 768) * 256 + k0 + 1], d1, true);
      uint2 o; o.x = (unsigned int)d0; o.y = (unsigned int)d1;
      WT8[idx] = o;
    }
#endif
    return;
  }
  int gid = blockIdx.x * 256 + threadIdx.x;      // 2*128*256 = 65536
  int d = gid >> 15;
  int rem = gid & 32767;
  int kk = rem >> 8, j = rem & 255;
  const float* W = d ? Whb : Whf;
  int k0 = kk * 2;
  uint4 o;
  o.x = pkh(W[(size_t)j * 256 + k0],         W[(size_t)j * 256 + k0 + 1]);
  o.y = pkh(W[(size_t)(j + 256) * 256 + k0], W[(size_t)(j + 256) * 256 + k0 + 1]);
  o.z = pkh(W[(size_t)(j + 512) * 256 + k0], W[(size_t)(j + 512) * 256 + k0 + 1]);
  o.w = pkh(W[(size_t)(j + 768) * 256 + k0], W[(size_t)(j + 768) * 256 + k0 + 1]);
  WT[gid] = o;
}

// ---------------------------------------------------------------- gemm_x (MFMA)
// (unchanged from round 10)
__global__ __launch_bounds__(256) void gemm_x(const int* __restrict__ sent,
                                              const float* __restrict__ emb,
                                              const float* __restrict__ Wf,
                                              const float* __restrict__ Wb,
                                              const float* __restrict__ bihf,
                                              const float* __restrict__ bhhf,
                                              const float* __restrict__ bihb,
                                              const float* __restrict__ bhhb,
                                              u16* __restrict__ X4) {
  __shared__ _Float16 A_lds[128][40];
  __shared__ _Float16 B_lds[64][40];
  __shared__ int tok[128];
  __shared__ u16 Xs[128][80];
  int tid = threadIdx.x;
  int in = blockIdx.x;                 // 0..31
  int im = blockIdx.y;                 // 0..127
  int d = in >> 4, j0 = (in & 15) * 16;
  if (tid < 128) tok[tid] = sent[im * 128 + tid];

  int w = tid >> 6, l = tid & 63;
  int lrow = l & 15, lk = l >> 4;
  f32x4 acc[2][4];
#pragma unroll
  for (int mt = 0; mt < 2; ++mt)
#pragma unroll
    for (int nt = 0; nt < 4; ++nt) acc[mt][nt] = (f32x4)0.0f;

  int arow = tid >> 1, akh = tid & 1;
  int brow = tid & 63, bkq = tid >> 6;
  int r_w = ((brow >> 4) << 8) + j0 + (brow & 15);   // gate*256 + j
  const float* wrow = (d ? Wb : Wf) + (size_t)r_w * 256;

  for (int kc = 0; kc < 8; ++kc) {
    int k0 = kc * 32;
    __syncthreads();
    {
      const float* ap = emb + (size_t)tok[arow] * 256 + k0 + akh * 16;
#pragma unroll
      for (int q = 0; q < 2; ++q) {
        float4 v0 = *(const float4*)(ap + q * 8);
        float4 v1 = *(const float4*)(ap + q * 8 + 4);
        uint4 pk;
        pk.x = pkh(v0.x, v0.y); pk.y = pkh(v0.z, v0.w);
        pk.z = pkh(v1.x, v1.y); pk.w = pkh(v1.z, v1.w);
        *(uint4*)&A_lds[arow][akh * 16 + q * 8] = pk;
      }
    }
    {
      float4 v0 = *(const float4*)(wrow + k0 + bkq * 8);
      float4 v1 = *(const float4*)(wrow + k0 + bkq * 8 + 4);
      uint4 pk;
      pk.x = pkh(v0.x, v0.y); pk.y = pkh(v0.z, v0.w);
      pk.z = pkh(v1.x, v1.y); pk.w = pkh(v1.z, v1.w);
      *(uint4*)&B_lds[brow][bkq * 8] = pk;
    }
    __syncthreads();
    half8 af[2], bf[4];
#pragma unroll
    for (int mt = 0; mt < 2; ++mt)
      af[mt] = *(const half8*)&A_lds[w * 32 + mt * 16 + lrow][lk * 8];
#pragma unroll
    for (int nt = 0; nt < 4; ++nt)
      bf[nt] = *(const half8*)&B_lds[nt * 16 + lrow][lk * 8];
#pragma unroll
    for (int mt = 0; mt < 2; ++mt)
#pragma unroll
      for (int nt = 0; nt < 4; ++nt)
        acc[mt][nt] = __builtin_amdgcn_mfma_f32_16x16x32_f16(af[mt], bf[nt], acc[mt][nt], 0, 0, 0);
  }
  float bias[4];
#pragma unroll
  for (int nt = 0; nt < 4; ++nt) {
    int rr = nt * 256 + j0 + lrow;
    bias[nt] = d ? (bihb[rr] + bhhb[rr]) : (bihf[rr] + bhhf[rr]);
  }
  __syncthreads();
#pragma unroll
  for (int mt = 0; mt < 2; ++mt)
#pragma unroll
    for (int r = 0; r < 4; ++r) {
      int row = w * 32 + mt * 16 + lk * 4 + r;
      uint2 pk;
      pk.x = (unsigned int)f2b(acc[mt][0][r] + bias[0]) |
             ((unsigned int)f2b(acc[mt][1][r] + bias[1]) << 16);
      pk.y = (unsigned int)f2b(acc[mt][2][r] + bias[2]) |
             ((unsigned int)f2b(acc[mt][3][r] + bias[3]) << 16);
      *(uint2*)&Xs[row][lrow * 4] = pk;
    }
  __syncthreads();
  int frow = tid >> 1, fh = tid & 1;
  int i = im * 128 + frow;
  int bb = i >> 8, tt = i & 255;
  size_t base = (((size_t)d * NT + tt) * NB + bb) * 1024 + (size_t)j0 * 4 + fh * 32;
#pragma unroll
  for (int q = 0; q < 4; ++q)
    *(uint4*)&X4[base + q * 8] = *(const uint4*)&Xs[frow][fh * 32 + q * 8];
}

// ---------------------------------------------------------------- lstm_scan
// R10 structure; slab + streamed regions fp8 when available (reg region f16).
__global__ __launch_bounds__(1024, 4) void lstm_scan(const uint4* __restrict__ WT,
                                                     const uint2* __restrict__ WT8,
                                                     const ushort4* __restrict__ X4,
                                                     const float* __restrict__ h0,
                                                     const float* __restrict__ c0,
                                                     u16* __restrict__ H) {
  int d = blockIdx.x >> 6, b = blockIdx.x & 63;
  int tid = threadIdx.x;
  int jj = tid & 255, g = tid >> 8;
  __shared__ uint4 h2s4[32];            // packed f16 h pairs (reg region)
  __shared__ float4 plds[3][256];
#if HAS_FP8
  __shared__ uint2 wlds8[KK_SLAB * 256];  // 64 KB fp8 slab
  __shared__ float hf32[256];             // f32 h mirror for fp8 fma
  const uint2* W8 = WT8 + (size_t)d * 16384;
  for (int e = tid; e < KK_SLAB * 256; e += 1024) wlds8[e] = W8[e];
#else
  __shared__ uint4 wlds[KK_SLAB * 256];   // 128 KB f16 slab
#endif
  const uint4* Ws = WT + (size_t)d * 32768;
#if !HAS_FP8
  for (int e = tid; e < KK_SLAB * 256; e += 1024) wlds[e] = Ws[e];
#endif
  uint4 wreg[KK_REG];
#pragma unroll
  for (int r = 0; r < KK_REG; ++r)
    wreg[r] = Ws[(size_t)(KK_SLAB + g * KK_REG + r) * 256 + jj];
  float c = 0.f;
  if (g == 0) c = c0[((size_t)d * NB + b) * 256 + jj];
  if (tid < 256) {
    float hv = h0[((size_t)d * NB + b) * 256 + tid];
    ((u16*)h2s4)[tid] = f2h(hv);
#if HAS_FP8
    hf32[tid] = hv;
#endif
  }
  __syncthreads();
  for (int s = 0; s < NT; ++s) {
    int t = d ? (NT - 1 - s) : s;
    ushort4 xg = make_ushort4(0, 0, 0, 0);
    if (g == 0) xg = X4[(((size_t)d * NT + t) * NB + b) * 256 + jj];
    float ai = 0.f, af = 0.f, ag = 0.f, ao = 0.f;
#if HAS_FP8
    const float4* hf4 = (const float4*)hf32;
    // streamed fp8: kk = 96+g*8+u; h elems 192+g*16.. -> hf4[48+g*4 ..+4)
    {
      float4 a0 = hf4[48 + g * 4], a1 = hf4[48 + g * 4 + 1];
      float4 a2 = hf4[48 + g * 4 + 2], a3 = hf4[48 + g * 4 + 3];
      float hv[8 * 2] = {a0.x, a0.y, a0.z, a0.w, a1.x, a1.y, a1.z, a1.w,
                         a2.x, a2.y, a2.z, a2.w, a3.x, a3.y, a3.z, a3.w};
      const uint2* Wst = W8 + (size_t)(32 + g * 8) * 256 + jj;
#pragma unroll
      for (int u = 0; u < KK_STRM; ++u) {
        uint2 wv = Wst[(size_t)u * 256];
        f32x2 pif0 = __builtin_amdgcn_cvt_pk_f32_fp8(wv.x, false);
        f32x2 pgo0 = __builtin_amdgcn_cvt_pk_f32_fp8(wv.x, true);
        f32x2 pif1 = __builtin_amdgcn_cvt_pk_f32_fp8(wv.y, false);
        f32x2 pgo1 = __builtin_amdgcn_cvt_pk_f32_fp8(wv.y, true);
        float hA = hv[2 * u], hB = hv[2 * u + 1];
        ai += pif0.x * hA + pif1.x * hB;
        af += pif0.y * hA + pif1.y * hB;
        ag += pgo0.x * hA + pgo1.x * hB;
        ao += pgo0.y * hA + pgo1.y * hB;
      }
    }
    // slab fp8 (LDS): kk = g*8+r; h elems 2*(g*8).. -> hf4[g*4 ..+4)
    {
      float4 a0 = hf4[g * 4], a1 = hf4[g * 4 + 1];
      float4 a2 = hf4[g * 4 + 2], a3 = hf4[g * 4 + 3];
      float hv[8 * 2] = {a0.x, a0.y, a0.z, a0.w, a1.x, a1.y, a1.z, a1.w,
                         a2.x, a2.y, a2.z, a2.w, a3.x, a3.y, a3.z, a3.w};
#pragma unroll
      for (int r = 0; r < 8; ++r) {
        uint2 wv = wlds8[((g * 8 + r) << 8) | jj];
        f32x2 pif0 = __builtin_amdgcn_cvt_pk_f32_fp8(wv.x, false);
        f32x2 pgo0 = __builtin_amdgcn_cvt_pk_f32_fp8(wv.x, true);
        f32x2 pif1 = __builtin_amdgcn_cvt_pk_f32_fp8(wv.y, false);
        f32x2 pgo1 = __builtin_amdgcn_cvt_pk_f32_fp8(wv.y, true);
        float hA = hv[2 * r], hB = hv[2 * r + 1];
        ai += pif0.x * hA + pif1.x * hB;
        af += pif0.y * hA + pif1.y * hB;
        ag += pgo0.x * hA + pgo1.x * hB;
        ao += pgo0.y * hA + pgo1.y * hB;
      }
    }
#else
    // streamed f16 (R10): kk = 96+g*8+u
    {
      uint4 hc0 = h2s4[24 + g * 2], hc1 = h2s4[24 + g * 2 + 1];
      unsigned int hp[8] = {hc0.x, hc0.y, hc0.z, hc0.w, hc1.x, hc1.y, hc1.z, hc1.w};
      const uint4* Wp_ = Ws + (size_t)(96 + g * 8) * 256 + jj;
#pragma unroll
      for (int u = 0; u < KK_STRM; ++u) {
        uint4 wv = Wp_[(size_t)u * 256];
        ai = dot2h(wv.x, hp[u], ai); af = dot2h(wv.y, hp[u], af);
        ag = dot2h(wv.z, hp[u], ag); ao = dot2h(wv.w, hp[u], ao);
      }
    }
    // slab f16 (R10): kk = g*8+r
    {
      uint4 ha0 = h2s4[g * 2], ha1 = h2s4[g * 2 + 1];
      unsigned int hp[8] = {ha0.x, ha0.y, ha0.z, ha0.w, ha1.x, ha1.y, ha1.z, ha1.w};
#pragma unroll
      for (int r = 0; r < 8; ++r) {
        uint4 wv = wlds[((g * 8 + r) << 8) | jj];
        ai = dot2h(wv.x, hp[r], ai); af = dot2h(wv.y, hp[r], af);
        ag = dot2h(wv.z, hp[r], ag); ao = dot2h(wv.w, hp[r], ao);
      }
    }
#endif
    // register region f16 (unchanged): kk = 32+g*16+r
    {
      uint4 hb0 = h2s4[8 + g * 4], hb1 = h2s4[8 + g * 4 + 1];
      uint4 hb2 = h2s4[8 + g * 4 + 2], hb3 = h2s4[8 + g * 4 + 3];
      unsigned int hp[16] = {hb0.x, hb0.y, hb0.z, hb0.w, hb1.x, hb1.y, hb1.z, hb1.w,
                             hb2.x, hb2.y, hb2.z, hb2.w, hb3.x, hb3.y, hb3.z, hb3.w};
#pragma unroll
      for (int r = 0; r < KK_REG; ++r) {
        uint4 wv = wreg[r];
        ai = dot2h(wv.x, hp[r], ai); af = dot2h(wv.y, hp[r], af);
        ag = dot2h(wv.z, hp[r], ag); ao = dot2h(wv.w, hp[r], ao);
      }
    }
    if (g) plds[g - 1][jj] = make_float4(ai, af, ag, ao);
    __syncthreads();
    if (g == 0) {
      float4 p0 = plds[0][jj], p1 = plds[1][jj], p2 = plds[2][jj];
      ai += p0.x + p1.x + p2.x + b2f(xg.x);
      af += p0.y + p1.y + p2.y + b2f(xg.y);
      ag += p0.z + p1.z + p2.z + b2f(xg.z);
      ao += p0.w + p1.w + p2.w + b2f(xg.w);
      float ii = fsig(ai), ff = fsig(af), gg = ftanh(ag), oo = fsig(ao);
      c = ff * c + ii * gg;
      float h = oo * ftanh(c);
      u16 hu = f2h(h);
      ((u16*)h2s4)[jj] = hu;
#if HAS_FP8
      hf32[jj] = h;
#endif
      H[(((size_t)d * NB + b) * NT + t) * 256 + jj] = hu;
    }
    __syncthreads();
  }
}

// ---------------------------------------------------------------- feats
// (unchanged from round 10)
__global__ __launch_bounds__(384) void feats_kernel(const u16* __restrict__ H,
                                                    const unsigned int* __restrict__ WpH,
                                                    const float* __restrict__ bp,
                                                    float* __restrict__ FT) {
  __shared__ uint4 hbuf[32][65];
  __shared__ uint4 wbuf[64][12];
  int tid = threadIdx.x;
  int i0 = blockIdx.x * 32;
  for (int idx = tid; idx < 768; idx += 384) {
    int it = idx / 12, k = idx - it * 12;
    wbuf[it][k] = ((const uint4*)WpH)[k * 64 + it];
  }
  for (int idx = tid; idx < 2048; idx += 384) {
    int row = idx >> 6, c4 = idx & 63;
    int i = i0 + row;
    int b = i >> 8, t = i & 255;
    int dd = c4 >> 5, cc = c4 & 31;
    const uint4* hpg = (const uint4*)(H + (((size_t)dd * NB + b) * NT + t) * 256);
    hbuf[row][c4] = hpg[cc];
  }
  __syncthreads();
  int row = tid / 12, k = tid - row * 12;
  float s = 0.f;
#pragma unroll 8
  for (int it = 0; it < 64; ++it) {
    uint4 h4 = hbuf[row][it];
    uint4 w4 = wbuf[it][k];
    s = dot2h(h4.x, w4.x, s); s = dot2h(h4.y, w4.y, s);
    s = dot2h(h4.z, w4.z, s); s = dot2h(h4.w, w4.w, s);
  }
  int i = i0 + row;
  FT[(size_t)i * NKTAG + k] = s + bp[k];
}

// ---------------------------------------------------------------- viterbi
__global__ __launch_bounds__(64) void viterbi_kernel(const float* __restrict__ FT,
                                                     const float* __restrict__ trans,
                                                     const int* __restrict__ sent,
                                                     float* __restrict__ out) {
  int b = blockIdx.x, tid = threadIdx.x;
  __shared__ float trans_s[12][12];
  __shared__ float s_s[12];
  __shared__ unsigned char bp_s[256][12];
  __shared__ int path_s[256];
  for (int idx = tid; idx < 144; idx += 64) trans_s[idx / 12][idx % 12] = trans[idx];
  int cnt = 0;
#pragma unroll
  for (int q = 0; q < 4; ++q) cnt += (sent[b * NT + q * 64 + tid] > 0) ? 1 : 0;
  for (int off = 32; off; off >>= 1) cnt += __shfl_down(cnt, off);
  int len = __shfl(cnt, 0);
  if (tid < 12) s_s[tid] = (tid == START_TAG) ? 0.f : -10000.f;
  __syncthreads();
  for (int t = 0; t < NT; ++t) {
    float best = 0.f, f = 0.f;
    int barg = 0;
    if (tid < 12) {
      f = FT[((size_t)b * NT + t) * NKTAG + tid];
      best = s_s[0] + trans_s[tid][0];
      barg = 0;
#pragma unroll
      for (int fr = 1; fr < 12; ++fr) {
        float v = s_s[fr] + trans_s[tid][fr];
        if (v > best) { best = v; barg = fr; }  // strict > keeps first (jnp.argmax)
      }
    }
    __syncthreads();
    if (tid < 12) {
      s_s[tid] = best + f;
      bp_s[t][tid] = (unsigned char)barg;
    }
    __syncthreads();
  }
  if (tid == 0) {
    float bs = s_s[0];
    int bt = 0;
    for (int k = 1; k < 12; ++k)
      if (s_s[k] > bs) { bs = s_s[k]; bt = k; }
    out[NB * NT + b] = bs;
    int x = bt;
    for (int tt = NT - 1; tt >= 0; --tt) {
      path_s[tt] = x;
      int nxt = bp_s[tt][x];
      if (tt < len) x = nxt;
    }
  }
  __syncthreads();
#pragma unroll
  for (int q = 0; q < 4; ++q) {
    int t = q * 64 + tid;
    out[b * NT + t] = (t < len) ? (float)path_s[t] : -1.0f;
  }
}

// ---------------------------------------------------------------- launch
extern "C" void kernel_launch(void* const* d_in, const int* in_sizes, int n_in,
                              void* d_out, int out_size, void* d_ws, size_t ws_size,
                              hipStream_t stream) {
  (void)in_sizes; (void)n_in; (void)out_size; (void)ws_size;
  const int*   sent  = (const int*)d_in[0];
  const float* emb   = (const float*)d_in[2];
  const float* Wih_f = (const float*)d_in[3];
  const float* Whh_f = (const float*)d_in[4];
  const float* bih_f = (const float*)d_in[5];
  const float* bhh_f = (const float*)d_in[6];
  const float* Wih_b = (const float*)d_in[7];
  const float* Whh_b = (const float*)d_in[8];
  const float* bih_b = (const float*)d_in[9];
  const float* bhh_b = (const float*)d_in[10];
  const float* Wp    = (const float*)d_in[11];
  const float* bp    = (const float*)d_in[12];
  const float* trans = (const float*)d_in[13];
  const float* h0    = (const float*)d_in[14];
  const float* c0    = (const float*)d_in[15];
  float* out = (float*)d_out;

  char* w = (char*)d_ws;
  u16*   X4  = (u16*)w;                                      // 67108864 B
  uint4* WTH = (uint4*)(w + 67108864);                       //  1048576 B
  float* FT  = (float*)(w + 68157440);                       //   786432 B
  unsigned int* WpH = (unsigned int*)(w + 68943872);         //    12288 B
  u16*   H   = (u16*)(w + 68956160);                         // 16777216 B
  uint2* WT8 = (uint2*)(w + 85733376);                       //   262144 B

  pack_whh<<<dim3(258), dim3(256), 0, stream>>>(Whh_f, Whh_b, Wp, WTH, WpH, WT8);
  gemm_x<<<dim3(32, 128), dim3(256), 0, stream>>>(sent, emb, Wih_f, Wih_b,
                                                  bih_f, bhh_f, bih_b, bhh_b, X4);
  lstm_scan<<<dim3(128), dim3(1024), 0, stream>>>(WTH, WT8, (const ushort4*)X4,
                                                  h0, c0, H);
  feats_kernel<<<dim3(512), dim3(384), 0, stream>>>(H, WpH, bp, FT);
  viterbi_kernel<<<dim3(64), dim3(64), 0, stream>>>(FT, trans, sent, out);
}

// Round 13
// 602.015 us; speedup vs baseline: 3.0684x; 3.0684x over previous
//
#include <hip/hip_runtime.h>

// BiLSTM-CRF on MI355X — round 13: R10 base (fp8 R12 reverted — cvt-chain
// serialization tripled the scan) + three non-scan fixes:
//  * gemm_x: bijective XCD swizzle (consecutive N-tiles of one A-tile land on
//    one XCD -> A read from L3 once per XCD, not 32x)
//  * viterbi: FT row prefetch (breaks the serial L2-latency chain, ~200cy/step)
//  * feats: 4 independent accumulators (breaks 256-deep dot2 dependency chain)
//
// ws layout: X4 (67108864) | WTH (1048576) | FT (786432) | WpH (12288) |
//            H u16 (16777216)  = 85.7 MB total.
// Output (float32): d_out[0:16384] = paths (floats, -1 past length), [16384:16448] = best_score.

#define NB 64
#define NT 256
#define NKTAG 12
#define START_TAG 10
#define KK_SLAB 32
#define KK_REG 16
#define KK_STRM 8

typedef unsigned short u16;
typedef _Float16 half2v __attribute__((ext_vector_type(2)));
typedef _Float16 half8 __attribute__((ext_vector_type(8)));
typedef float f32x4 __attribute__((ext_vector_type(4)));

__device__ __forceinline__ float b2f(u16 u) {
  union { unsigned int i; float f; } v; v.i = ((unsigned int)u) << 16; return v.f;
}
__device__ __forceinline__ u16 f2b(float f) {
  union { float f; unsigned int i; } v; v.f = f;
  unsigned int r = v.i + 0x7FFFu + ((v.i >> 16) & 1u);
  return (u16)(r >> 16);
}
__device__ __forceinline__ u16 f2h(float f) {
  union { _Float16 h; u16 u; } v; v.h = (_Float16)f; return v.u;
}
__device__ __forceinline__ unsigned int pkh(float x, float y) {
  return (unsigned int)f2h(x) | ((unsigned int)f2h(y) << 16);
}
__device__ __forceinline__ float fsig(float x) { return 1.0f / (1.0f + __expf(-x)); }
__device__ __forceinline__ float ftanh(float x) { return 2.0f / (1.0f + __expf(-2.0f * x)) - 1.0f; }

__device__ __forceinline__ float dot2h(unsigned int a, unsigned int b, float c) {
#if __has_builtin(__builtin_amdgcn_fdot2)
  union { unsigned int u; half2v h; } va, vb;
  va.u = a; vb.u = b;
  return __builtin_amdgcn_fdot2(va.h, vb.h, c, false);
#else
  float d;
  asm("v_dot2_f32_f16 %0, %1, %2, %3" : "=v"(d) : "v"(a), "v"(b), "v"(c));
  return d;
#endif
}

// ---------------------------------------------------------------- pack_whh (+WpH)
__global__ __launch_bounds__(256) void pack_whh(const float* __restrict__ Whf,
                                                const float* __restrict__ Whb,
                                                const float* __restrict__ Wp,
                                                uint4* __restrict__ WT,
                                                unsigned int* __restrict__ WpH) {
  if (blockIdx.x == 256) {   // WpH: [12][256] packed f16 pairs of Wp[12][512]
    for (int it = 0; it < 12; ++it) {
      int idx = it * 256 + threadIdx.x;
      int k = idx >> 8, cc = idx & 255;
      WpH[idx] = pkh(Wp[(size_t)k * 512 + 2 * cc], Wp[(size_t)k * 512 + 2 * cc + 1]);
    }
    return;
  }
  int gid = blockIdx.x * 256 + threadIdx.x;      // 2*128*256 = 65536
  int d = gid >> 15;
  int rem = gid & 32767;
  int kk = rem >> 8, j = rem & 255;
  const float* W = d ? Whb : Whf;
  int k0 = kk * 2;
  uint4 o;
  o.x = pkh(W[(size_t)j * 256 + k0],         W[(size_t)j * 256 + k0 + 1]);
  o.y = pkh(W[(size_t)(j + 256) * 256 + k0], W[(size_t)(j + 256) * 256 + k0 + 1]);
  o.z = pkh(W[(size_t)(j + 512) * 256 + k0], W[(size_t)(j + 512) * 256 + k0 + 1]);
  o.w = pkh(W[(size_t)(j + 768) * 256 + k0], W[(size_t)(j + 768) * 256 + k0 + 1]);
  WT[gid] = o;
}

// ---------------------------------------------------------------- gemm_x (MFMA)
// Block: M=128 (one b, 128 consecutive t), N=64 = 16 j x 4 gates, one dir.
// XCD swizzle: lin = by*32+bx; swz = (lin%8)*512 + lin/8 (bijective, 4096=8*512)
// -> each XCD gets 512 consecutive swz = 16 im values x all 32 in; the 32
// N-tile blocks sharing one A-tile co-run on one XCD's L2.
__global__ __launch_bounds__(256) void gemm_x(const int* __restrict__ sent,
                                              const float* __restrict__ emb,
                                              const float* __restrict__ Wf,
                                              const float* __restrict__ Wb,
                                              const float* __restrict__ bihf,
                                              const float* __restrict__ bhhf,
                                              const float* __restrict__ bihb,
                                              const float* __restrict__ bhhb,
                                              u16* __restrict__ X4) {
  __shared__ _Float16 A_lds[128][40];
  __shared__ _Float16 B_lds[64][40];
  __shared__ int tok[128];
  __shared__ u16 Xs[128][80];
  int tid = threadIdx.x;
  int lin = blockIdx.y * 32 + blockIdx.x;
  int swz = (lin & 7) * 512 + (lin >> 3);
  int in = swz & 31;                   // 0..31
  int im = swz >> 5;                   // 0..127
  int d = in >> 4, j0 = (in & 15) * 16;
  if (tid < 128) tok[tid] = sent[im * 128 + tid];

  int w = tid >> 6, l = tid & 63;
  int lrow = l & 15, lk = l >> 4;
  f32x4 acc[2][4];
#pragma unroll
  for (int mt = 0; mt < 2; ++mt)
#pragma unroll
    for (int nt = 0; nt < 4; ++nt) acc[mt][nt] = (f32x4)0.0f;

  int arow = tid >> 1, akh = tid & 1;
  int brow = tid & 63, bkq = tid >> 6;
  int r_w = ((brow >> 4) << 8) + j0 + (brow & 15);   // gate*256 + j
  const float* wrow = (d ? Wb : Wf) + (size_t)r_w * 256;

  for (int kc = 0; kc < 8; ++kc) {
    int k0 = kc * 32;
    __syncthreads();
    {
      const float* ap = emb + (size_t)tok[arow] * 256 + k0 + akh * 16;
#pragma unroll
      for (int q = 0; q < 2; ++q) {
        float4 v0 = *(const float4*)(ap + q * 8);
        float4 v1 = *(const float4*)(ap + q * 8 + 4);
        uint4 pk;
        pk.x = pkh(v0.x, v0.y); pk.y = pkh(v0.z, v0.w);
        pk.z = pkh(v1.x, v1.y); pk.w = pkh(v1.z, v1.w);
        *(uint4*)&A_lds[arow][akh * 16 + q * 8] = pk;
      }
    }
    {
      float4 v0 = *(const float4*)(wrow + k0 + bkq * 8);
      float4 v1 = *(const float4*)(wrow + k0 + bkq * 8 + 4);
      uint4 pk;
      pk.x = pkh(v0.x, v0.y); pk.y = pkh(v0.z, v0.w);
      pk.z = pkh(v1.x, v1.y); pk.w = pkh(v1.z, v1.w);
      *(uint4*)&B_lds[brow][bkq * 8] = pk;
    }
    __syncthreads();
    half8 af[2], bf[4];
#pragma unroll
    for (int mt = 0; mt < 2; ++mt)
      af[mt] = *(const half8*)&A_lds[w * 32 + mt * 16 + lrow][lk * 8];
#pragma unroll
    for (int nt = 0; nt < 4; ++nt)
      bf[nt] = *(const half8*)&B_lds[nt * 16 + lrow][lk * 8];
#pragma unroll
    for (int mt = 0; mt < 2; ++mt)
#pragma unroll
      for (int nt = 0; nt < 4; ++nt)
        acc[mt][nt] = __builtin_amdgcn_mfma_f32_16x16x32_f16(af[mt], bf[nt], acc[mt][nt], 0, 0, 0);
  }
  float bias[4];
#pragma unroll
  for (int nt = 0; nt < 4; ++nt) {
    int rr = nt * 256 + j0 + lrow;
    bias[nt] = d ? (bihb[rr] + bhhb[rr]) : (bihf[rr] + bhhf[rr]);
  }
  __syncthreads();
#pragma unroll
  for (int mt = 0; mt < 2; ++mt)
#pragma unroll
    for (int r = 0; r < 4; ++r) {
      int row = w * 32 + mt * 16 + lk * 4 + r;
      uint2 pk;
      pk.x = (unsigned int)f2b(acc[mt][0][r] + bias[0]) |
             ((unsigned int)f2b(acc[mt][1][r] + bias[1]) << 16);
      pk.y = (unsigned int)f2b(acc[mt][2][r] + bias[2]) |
             ((unsigned int)f2b(acc[mt][3][r] + bias[3]) << 16);
      *(uint2*)&Xs[row][lrow * 4] = pk;
    }
  __syncthreads();
  int frow = tid >> 1, fh = tid & 1;
  int i = im * 128 + frow;
  int bb = i >> 8, tt = i & 255;
  size_t base = (((size_t)d * NT + tt) * NB + bb) * 1024 + (size_t)j0 * 4 + fh * 32;
#pragma unroll
  for (int q = 0; q < 4; ++q)
    *(uint4*)&X4[base + q * 8] = *(const uint4*)&Xs[frow][fh * 32 + q * 8];
}

// ---------------------------------------------------------------- lstm_scan
// (byte-identical R10 structure — the proven 453us control)
__global__ __launch_bounds__(1024, 4) void lstm_scan(const uint4* __restrict__ WT,
                                                     const ushort4* __restrict__ X4,
                                                     const float* __restrict__ h0,
                                                     const float* __restrict__ c0,
                                                     u16* __restrict__ H) {
  int d = blockIdx.x >> 6, b = blockIdx.x & 63;
  int tid = threadIdx.x;
  int jj = tid & 255, g = tid >> 8;
  __shared__ uint4 wlds[KK_SLAB * 256];
  __shared__ uint4 h2s4[32];
  __shared__ float4 plds[3][256];
  const uint4* Ws = WT + (size_t)d * 32768;
  for (int e = tid; e < KK_SLAB * 256; e += 1024) wlds[e] = Ws[e];
  uint4 wreg[KK_REG];
#pragma unroll
  for (int r = 0; r < KK_REG; ++r)
    wreg[r] = Ws[(size_t)(KK_SLAB + g * KK_REG + r) * 256 + jj];
  float c = 0.f;
  if (g == 0) c = c0[((size_t)d * NB + b) * 256 + jj];
  if (tid < 256) ((u16*)h2s4)[tid] = f2h(h0[((size_t)d * NB + b) * 256 + tid]);
  __syncthreads();
  for (int s = 0; s < NT; ++s) {
    int t = d ? (NT - 1 - s) : s;
    ushort4 xg = make_ushort4(0, 0, 0, 0);
    if (g == 0) xg = X4[(((size_t)d * NT + t) * NB + b) * 256 + jj];
    float ai = 0.f, af = 0.f, ag = 0.f, ao = 0.f;
    {
      uint4 hc0 = h2s4[24 + g * 2], hc1 = h2s4[24 + g * 2 + 1];
      unsigned int hp[8] = {hc0.x, hc0.y, hc0.z, hc0.w, hc1.x, hc1.y, hc1.z, hc1.w};
      const uint4* Wp_ = Ws + (size_t)(96 + g * 8) * 256 + jj;
#pragma unroll
      for (int u = 0; u < KK_STRM; ++u) {
        uint4 wv = Wp_[(size_t)u * 256];
        ai = dot2h(wv.x, hp[u], ai); af = dot2h(wv.y, hp[u], af);
        ag = dot2h(wv.z, hp[u], ag); ao = dot2h(wv.w, hp[u], ao);
      }
    }
    {
      uint4 ha0 = h2s4[g * 2], ha1 = h2s4[g * 2 + 1];
      unsigned int hp[8] = {ha0.x, ha0.y, ha0.z, ha0.w, ha1.x, ha1.y, ha1.z, ha1.w};
#pragma unroll
      for (int r = 0; r < 8; ++r) {
        uint4 wv = wlds[((g * 8 + r) << 8) | jj];
        ai = dot2h(wv.x, hp[r], ai); af = dot2h(wv.y, hp[r], af);
        ag = dot2h(wv.z, hp[r], ag); ao = dot2h(wv.w, hp[r], ao);
      }
    }
    {
      uint4 hb0 = h2s4[8 + g * 4], hb1 = h2s4[8 + g * 4 + 1];
      uint4 hb2 = h2s4[8 + g * 4 + 2], hb3 = h2s4[8 + g * 4 + 3];
      unsigned int hp[16] = {hb0.x, hb0.y, hb0.z, hb0.w, hb1.x, hb1.y, hb1.z, hb1.w,
                             hb2.x, hb2.y, hb2.z, hb2.w, hb3.x, hb3.y, hb3.z, hb3.w};
#pragma unroll
      for (int r = 0; r < KK_REG; ++r) {
        uint4 wv = wreg[r];
        ai = dot2h(wv.x, hp[r], ai); af = dot2h(wv.y, hp[r], af);
        ag = dot2h(wv.z, hp[r], ag); ao = dot2h(wv.w, hp[r], ao);
      }
    }
    if (g) plds[g - 1][jj] = make_float4(ai, af, ag, ao);
    __syncthreads();
    if (g == 0) {
      float4 p0 = plds[0][jj], p1 = plds[1][jj], p2 = plds[2][jj];
      ai += p0.x + p1.x + p2.x + b2f(xg.x);
      af += p0.y + p1.y + p2.y + b2f(xg.y);
      ag += p0.z + p1.z + p2.z + b2f(xg.z);
      ao += p0.w + p1.w + p2.w + b2f(xg.w);
      float ii = fsig(ai), ff = fsig(af), gg = ftanh(ag), oo = fsig(ao);
      c = ff * c + ii * gg;
      float h = oo * ftanh(c);
      u16 hu = f2h(h);
      ((u16*)h2s4)[jj] = hu;
      H[(((size_t)d * NB + b) * NT + t) * 256 + jj] = hu;
    }
    __syncthreads();
  }
}

// ---------------------------------------------------------------- feats
// feats[b][t][k] = [hf|hb] . Wp[k] + bp[k]; 4 independent accumulators.
__global__ __launch_bounds__(384) void feats_kernel(const u16* __restrict__ H,
                                                    const unsigned int* __restrict__ WpH,
                                                    const float* __restrict__ bp,
                                                    float* __restrict__ FT) {
  __shared__ uint4 hbuf[32][65];
  __shared__ uint4 wbuf[64][12];
  int tid = threadIdx.x;
  int i0 = blockIdx.x * 32;
  for (int idx = tid; idx < 768; idx += 384) {
    int it = idx / 12, k = idx - it * 12;
    wbuf[it][k] = ((const uint4*)WpH)[k * 64 + it];
  }
  for (int idx = tid; idx < 2048; idx += 384) {
    int row = idx >> 6, c4 = idx & 63;
    int i = i0 + row;
    int b = i >> 8, t = i & 255;
    int dd = c4 >> 5, cc = c4 & 31;
    const uint4* hpg = (const uint4*)(H + (((size_t)dd * NB + b) * NT + t) * 256);
    hbuf[row][c4] = hpg[cc];
  }
  __syncthreads();
  int row = tid / 12, k = tid - row * 12;
  float s0 = 0.f, s1 = 0.f, s2 = 0.f, s3 = 0.f;
#pragma unroll 8
  for (int it = 0; it < 64; ++it) {
    uint4 h4 = hbuf[row][it];
    uint4 w4 = wbuf[it][k];
    s0 = dot2h(h4.x, w4.x, s0); s1 = dot2h(h4.y, w4.y, s1);
    s2 = dot2h(h4.z, w4.z, s2); s3 = dot2h(h4.w, w4.w, s3);
  }
  int i = i0 + row;
  FT[(size_t)i * NKTAG + k] = (s0 + s1) + (s2 + s3) + bp[k];
}

// ---------------------------------------------------------------- viterbi
// FT row prefetched 1 step ahead (load independent of DP state).
__global__ __launch_bounds__(64) void viterbi_kernel(const float* __restrict__ FT,
                                                     const float* __restrict__ trans,
                                                     const int* __restrict__ sent,
                                                     float* __restrict__ out) {
  int b = blockIdx.x, tid = threadIdx.x;
  __shared__ float trans_s[12][12];
  __shared__ float s_s[12];
  __shared__ unsigned char bp_s[256][12];
  __shared__ int path_s[256];
  for (int idx = tid; idx < 144; idx += 64) trans_s[idx / 12][idx % 12] = trans[idx];
  int cnt = 0;
#pragma unroll
  for (int q = 0; q < 4; ++q) cnt += (sent[b * NT + q * 64 + tid] > 0) ? 1 : 0;
  for (int off = 32; off; off >>= 1) cnt += __shfl_down(cnt, off);
  int len = __shfl(cnt, 0);
  if (tid < 12) s_s[tid] = (tid == START_TAG) ? 0.f : -10000.f;
  float f_next = (tid < 12) ? FT[((size_t)b * NT) * NKTAG + tid] : 0.f;
  __syncthreads();
  for (int t = 0; t < NT; ++t) {
    float best = 0.f, f = f_next;
    int barg = 0;
    if (t + 1 < NT && tid < 12)
      f_next = FT[((size_t)b * NT + t + 1) * NKTAG + tid];  // prefetch, state-indep
    if (tid < 12) {
      best = s_s[0] + trans_s[tid][0];
      barg = 0;
#pragma unroll
      for (int fr = 1; fr < 12; ++fr) {
        float v = s_s[fr] + trans_s[tid][fr];
        if (v > best) { best = v; barg = fr; }  // strict > keeps first (jnp.argmax)
      }
    }
    __syncthreads();
    if (tid < 12) {
      s_s[tid] = best + f;
      bp_s[t][tid] = (unsigned char)barg;
    }
    __syncthreads();
  }
  if (tid == 0) {
    float bs = s_s[0];
    int bt = 0;
    for (int k = 1; k < 12; ++k)
      if (s_s[k] > bs) { bs = s_s[k]; bt = k; }
    out[NB * NT + b] = bs;
    int x = bt;
    for (int tt = NT - 1; tt >= 0; --tt) {
      path_s[tt] = x;
      int nxt = bp_s[tt][x];
      if (tt < len) x = nxt;
    }
  }
  __syncthreads();
#pragma unroll
  for (int q = 0; q < 4; ++q) {
    int t = q * 64 + tid;
    out[b * NT + t] = (t < len) ? (float)path_s[t] : -1.0f;
  }
}

// ---------------------------------------------------------------- launch
extern "C" void kernel_launch(void* const* d_in, const int* in_sizes, int n_in,
                              void* d_out, int out_size, void* d_ws, size_t ws_size,
                              hipStream_t stream) {
  (void)in_sizes; (void)n_in; (void)out_size; (void)ws_size;
  const int*   sent  = (const int*)d_in[0];
  const float* emb   = (const float*)d_in[2];
  const float* Wih_f = (const float*)d_in[3];
  const float* Whh_f = (const float*)d_in[4];
  const float* bih_f = (const float*)d_in[5];
  const float* bhh_f = (const float*)d_in[6];
  const float* Wih_b = (const float*)d_in[7];
  const float* Whh_b = (const float*)d_in[8];
  const float* bih_b = (const float*)d_in[9];
  const float* bhh_b = (const float*)d_in[10];
  const float* Wp    = (const float*)d_in[11];
  const float* bp    = (const float*)d_in[12];
  const float* trans = (const float*)d_in[13];
  const float* h0    = (const float*)d_in[14];
  const float* c0    = (const float*)d_in[15];
  float* out = (float*)d_out;

  char* w = (char*)d_ws;
  u16*   X4  = (u16*)w;                                      // 67108864 B
  uint4* WTH = (uint4*)(w + 67108864);                       //  1048576 B
  float* FT  = (float*)(w + 68157440);                       //   786432 B
  unsigned int* WpH = (unsigned int*)(w + 68943872);         //    12288 B
  u16*   H   = (u16*)(w + 68956160);                         // 16777216 B

  pack_whh<<<dim3(257), dim3(256), 0, stream>>>(Whh_f, Whh_b, Wp, WTH, WpH);
  gemm_x<<<dim3(32, 128), dim3(256), 0, stream>>>(sent, emb, Wih_f, Wih_b,
                                                  bih_f, bhh_f, bih_b, bhh_b, X4);
  lstm_scan<<<dim3(128), dim3(1024), 0, stream>>>(WTH, (const ushort4*)X4, h0, c0, H);
  feats_kernel<<<dim3(512), dim3(384), 0, stream>>>(H, WpH, bp, FT);
  viterbi_kernel<<<dim3(64), dim3(64), 0, stream>>>(FT, trans, sent, out);
}

// Round 14
// 566.453 us; speedup vs baseline: 3.2610x; 1.0628x over previous
//
#include <hip/hip_runtime.h>

// BiLSTM-CRF on MI355X — round 14: full weight residency in the scan.
// 512-thread blocks (2 waves/SIMD -> 256-VGPR cap): group g in {0,1} owns
// kk [g*64, g*64+64) = 18 kk from a 144 KB LDS slab + 46 kk in registers
// (184 VGPR). ZERO per-step weight traffic (the 128 KB/step L2 stream --
// ~2340 cy, the R10 step's dominant term -- is gone). Non-scan kernels
// unchanged from R13.
//
// ws layout: X4 (67108864) | WTH (1048576) | FT (786432) | WpH (12288) |
//            H u16 (16777216)  = 85.7 MB total.
// Output (float32): d_out[0:16384] = paths (floats, -1 past length), [16384:16448] = best_score.

#define NB 64
#define NT 256
#define NKTAG 12
#define START_TAG 10
#define KK_SLAB2 18   // per-group LDS-slab kk (36 total = 147456 B)
#define KK_REG2 46    // per-group register kk (46 x uint4 = 184 VGPR)

typedef unsigned short u16;
typedef _Float16 half2v __attribute__((ext_vector_type(2)));
typedef _Float16 half8 __attribute__((ext_vector_type(8)));
typedef float f32x4 __attribute__((ext_vector_type(4)));

__device__ __forceinline__ float b2f(u16 u) {
  union { unsigned int i; float f; } v; v.i = ((unsigned int)u) << 16; return v.f;
}
__device__ __forceinline__ u16 f2b(float f) {
  union { float f; unsigned int i; } v; v.f = f;
  unsigned int r = v.i + 0x7FFFu + ((v.i >> 16) & 1u);
  return (u16)(r >> 16);
}
__device__ __forceinline__ u16 f2h(float f) {
  union { _Float16 h; u16 u; } v; v.h = (_Float16)f; return v.u;
}
__device__ __forceinline__ unsigned int pkh(float x, float y) {
  return (unsigned int)f2h(x) | ((unsigned int)f2h(y) << 16);
}
__device__ __forceinline__ float fsig(float x) { return 1.0f / (1.0f + __expf(-x)); }
__device__ __forceinline__ float ftanh(float x) { return 2.0f / (1.0f + __expf(-2.0f * x)) - 1.0f; }

__device__ __forceinline__ float dot2h(unsigned int a, unsigned int b, float c) {
#if __has_builtin(__builtin_amdgcn_fdot2)
  union { unsigned int u; half2v h; } va, vb;
  va.u = a; vb.u = b;
  return __builtin_amdgcn_fdot2(va.h, vb.h, c, false);
#else
  float d;
  asm("v_dot2_f32_f16 %0, %1, %2, %3" : "=v"(d) : "v"(a), "v"(b), "v"(c));
  return d;
#endif
}

// ---------------------------------------------------------------- pack_whh (+WpH)
__global__ __launch_bounds__(256) void pack_whh(const float* __restrict__ Whf,
                                                const float* __restrict__ Whb,
                                                const float* __restrict__ Wp,
                                                uint4* __restrict__ WT,
                                                unsigned int* __restrict__ WpH) {
  if (blockIdx.x == 256) {   // WpH: [12][256] packed f16 pairs of Wp[12][512]
    for (int it = 0; it < 12; ++it) {
      int idx = it * 256 + threadIdx.x;
      int k = idx >> 8, cc = idx & 255;
      WpH[idx] = pkh(Wp[(size_t)k * 512 + 2 * cc], Wp[(size_t)k * 512 + 2 * cc + 1]);
    }
    return;
  }
  int gid = blockIdx.x * 256 + threadIdx.x;      // 2*128*256 = 65536
  int d = gid >> 15;
  int rem = gid & 32767;
  int kk = rem >> 8, j = rem & 255;
  const float* W = d ? Whb : Whf;
  int k0 = kk * 2;
  uint4 o;
  o.x = pkh(W[(size_t)j * 256 + k0],         W[(size_t)j * 256 + k0 + 1]);
  o.y = pkh(W[(size_t)(j + 256) * 256 + k0], W[(size_t)(j + 256) * 256 + k0 + 1]);
  o.z = pkh(W[(size_t)(j + 512) * 256 + k0], W[(size_t)(j + 512) * 256 + k0 + 1]);
  o.w = pkh(W[(size_t)(j + 768) * 256 + k0], W[(size_t)(j + 768) * 256 + k0 + 1]);
  WT[gid] = o;
}

// ---------------------------------------------------------------- gemm_x (MFMA)
// (unchanged from round 13, incl. XCD swizzle)
__global__ __launch_bounds__(256) void gemm_x(const int* __restrict__ sent,
                                              const float* __restrict__ emb,
                                              const float* __restrict__ Wf,
                                              const float* __restrict__ Wb,
                                              const float* __restrict__ bihf,
                                              const float* __restrict__ bhhf,
                                              const float* __restrict__ bihb,
                                              const float* __restrict__ bhhb,
                                              u16* __restrict__ X4) {
  __shared__ _Float16 A_lds[128][40];
  __shared__ _Float16 B_lds[64][40];
  __shared__ int tok[128];
  __shared__ u16 Xs[128][80];
  int tid = threadIdx.x;
  int lin = blockIdx.y * 32 + blockIdx.x;
  int swz = (lin & 7) * 512 + (lin >> 3);
  int in = swz & 31;                   // 0..31
  int im = swz >> 5;                   // 0..127
  int d = in >> 4, j0 = (in & 15) * 16;
  if (tid < 128) tok[tid] = sent[im * 128 + tid];

  int w = tid >> 6, l = tid & 63;
  int lrow = l & 15, lk = l >> 4;
  f32x4 acc[2][4];
#pragma unroll
  for (int mt = 0; mt < 2; ++mt)
#pragma unroll
    for (int nt = 0; nt < 4; ++nt) acc[mt][nt] = (f32x4)0.0f;

  int arow = tid >> 1, akh = tid & 1;
  int brow = tid & 63, bkq = tid >> 6;
  int r_w = ((brow >> 4) << 8) + j0 + (brow & 15);   // gate*256 + j
  const float* wrow = (d ? Wb : Wf) + (size_t)r_w * 256;

  for (int kc = 0; kc < 8; ++kc) {
    int k0 = kc * 32;
    __syncthreads();
    {
      const float* ap = emb + (size_t)tok[arow] * 256 + k0 + akh * 16;
#pragma unroll
      for (int q = 0; q < 2; ++q) {
        float4 v0 = *(const float4*)(ap + q * 8);
        float4 v1 = *(const float4*)(ap + q * 8 + 4);
        uint4 pk;
        pk.x = pkh(v0.x, v0.y); pk.y = pkh(v0.z, v0.w);
        pk.z = pkh(v1.x, v1.y); pk.w = pkh(v1.z, v1.w);
        *(uint4*)&A_lds[arow][akh * 16 + q * 8] = pk;
      }
    }
    {
      float4 v0 = *(const float4*)(wrow + k0 + bkq * 8);
      float4 v1 = *(const float4*)(wrow + k0 + bkq * 8 + 4);
      uint4 pk;
      pk.x = pkh(v0.x, v0.y); pk.y = pkh(v0.z, v0.w);
      pk.z = pkh(v1.x, v1.y); pk.w = pkh(v1.z, v1.w);
      *(uint4*)&B_lds[brow][bkq * 8] = pk;
    }
    __syncthreads();
    half8 af[2], bf[4];
#pragma unroll
    for (int mt = 0; mt < 2; ++mt)
      af[mt] = *(const half8*)&A_lds[w * 32 + mt * 16 + lrow][lk * 8];
#pragma unroll
    for (int nt = 0; nt < 4; ++nt)
      bf[nt] = *(const half8*)&B_lds[nt * 16 + lrow][lk * 8];
#pragma unroll
    for (int mt = 0; mt < 2; ++mt)
#pragma unroll
      for (int nt = 0; nt < 4; ++nt)
        acc[mt][nt] = __builtin_amdgcn_mfma_f32_16x16x32_f16(af[mt], bf[nt], acc[mt][nt], 0, 0, 0);
  }
  float bias[4];
#pragma unroll
  for (int nt = 0; nt < 4; ++nt) {
    int rr = nt * 256 + j0 + lrow;
    bias[nt] = d ? (bihb[rr] + bhhb[rr]) : (bihf[rr] + bhhf[rr]);
  }
  __syncthreads();
#pragma unroll
  for (int mt = 0; mt < 2; ++mt)
#pragma unroll
    for (int r = 0; r < 4; ++r) {
      int row = w * 32 + mt * 16 + lk * 4 + r;
      uint2 pk;
      pk.x = (unsigned int)f2b(acc[mt][0][r] + bias[0]) |
             ((unsigned int)f2b(acc[mt][1][r] + bias[1]) << 16);
      pk.y = (unsigned int)f2b(acc[mt][2][r] + bias[2]) |
             ((unsigned int)f2b(acc[mt][3][r] + bias[3]) << 16);
      *(uint2*)&Xs[row][lrow * 4] = pk;
    }
  __syncthreads();
  int frow = tid >> 1, fh = tid & 1;
  int i = im * 128 + frow;
  int bb = i >> 8, tt = i & 255;
  size_t base = (((size_t)d * NT + tt) * NB + bb) * 1024 + (size_t)j0 * 4 + fh * 32;
#pragma unroll
  for (int q = 0; q < 4; ++q)
    *(uint4*)&X4[base + q * 8] = *(const uint4*)&Xs[frow][fh * 32 + q * 8];
}

// ---------------------------------------------------------------- lstm_scan
// 128 blocks x 512 threads = (jj 0..255, g 0..1); 2 waves/SIMD -> 256-VGPR cap.
// Group g owns kk [g*64, g*64+64): first 18 from LDS slab, 46 from registers.
// All 128 kk resident; per-step global traffic = X4 gates only (2 KB/block).
// h as packed-f16 pairs; unified 64-kk loop with compile-time kk index
// (slab/reg split resolved statically under full unroll).
__global__ __launch_bounds__(512, 2) void lstm_scan(const uint4* __restrict__ WT,
                                                    const ushort4* __restrict__ X4,
                                                    const float* __restrict__ h0,
                                                    const float* __restrict__ c0,
                                                    u16* __restrict__ H) {
  int d = blockIdx.x >> 6, b = blockIdx.x & 63;
  int tid = threadIdx.x;
  int jj = tid & 255, g = tid >> 8;       // g in 0..1
  __shared__ uint4 wlds[2 * KK_SLAB2 * 256];   // 147456 B slab
  __shared__ uint4 h2s4[32];                   // 512 B: 128 packed f16 h pairs
  __shared__ float4 plds[256];                 // 4096 B: g1 partials
  const uint4* Ws = WT + (size_t)d * 32768;    // [kk][j 0..255]
  // slab init: sr in [0,36): gg = sr/18, r = sr%18 -> kk = gg*64 + r
  for (int e = tid; e < 2 * KK_SLAB2 * 256; e += 512) {
    int sr = e >> 8, j2 = e & 255;
    int gg = sr / KK_SLAB2, r = sr - gg * KK_SLAB2;
    wlds[e] = Ws[(size_t)(gg * 64 + r) * 256 + j2];
  }
  // persistent register weights: kk = g*64 + 18 + r  (static unroll)
  uint4 wreg[KK_REG2];
#pragma unroll
  for (int r = 0; r < KK_REG2; ++r)
    wreg[r] = Ws[(size_t)(g * 64 + KK_SLAB2 + r) * 256 + jj];
  float c = 0.f;
  if (g == 0) c = c0[((size_t)d * NB + b) * 256 + jj];
  if (tid < 256) ((u16*)h2s4)[tid] = f2h(h0[((size_t)d * NB + b) * 256 + tid]);
  __syncthreads();
  for (int s = 0; s < NT; ++s) {
    int t = d ? (NT - 1 - s) : s;
    ushort4 xg = make_ushort4(0, 0, 0, 0);
    if (g == 0) xg = X4[(((size_t)d * NT + t) * NB + b) * 256 + jj];  // used at end
    float ai = 0.f, af = 0.f, ag = 0.f, ao = 0.f;
#pragma unroll
    for (int q = 0; q < 16; ++q) {
      uint4 h4 = h2s4[g * 16 + q];                 // uniform -> broadcast b128
      unsigned int hp[4] = {h4.x, h4.y, h4.z, h4.w};
#pragma unroll
      for (int e = 0; e < 4; ++e) {
        int kkl = q * 4 + e;                       // compile-time constant
        uint4 wv;
        if (kkl < KK_SLAB2) wv = wlds[((g * KK_SLAB2 + kkl) << 8) | jj];
        else                wv = wreg[kkl - KK_SLAB2];
        ai = dot2h(wv.x, hp[e], ai); af = dot2h(wv.y, hp[e], af);
        ag = dot2h(wv.z, hp[e], ag); ao = dot2h(wv.w, hp[e], ao);
      }
    }
    if (g) plds[jj] = make_float4(ai, af, ag, ao);
    __syncthreads();                   // partials visible; h2s4 reads done
    if (g == 0) {
      float4 p0 = plds[jj];
      ai += p0.x + b2f(xg.x);
      af += p0.y + b2f(xg.y);
      ag += p0.z + b2f(xg.z);
      ao += p0.w + b2f(xg.w);
      float ii = fsig(ai), ff = fsig(af), gg2 = ftanh(ag), oo = fsig(ao);
      c = ff * c + ii * gg2;
      float h = oo * ftanh(c);
      u16 hu = f2h(h);
      ((u16*)h2s4)[jj] = hu;
      H[(((size_t)d * NB + b) * NT + t) * 256 + jj] = hu;
    }
    __syncthreads();                   // h2s4 updated before next step
  }
}

// ---------------------------------------------------------------- feats
// (unchanged from round 13)
__global__ __launch_bounds__(384) void feats_kernel(const u16* __restrict__ H,
                                                    const unsigned int* __restrict__ WpH,
                                                    const float* __restrict__ bp,
                                                    float* __restrict__ FT) {
  __shared__ uint4 hbuf[32][65];
  __shared__ uint4 wbuf[64][12];
  int tid = threadIdx.x;
  int i0 = blockIdx.x * 32;
  for (int idx = tid; idx < 768; idx += 384) {
    int it = idx / 12, k = idx - it * 12;
    wbuf[it][k] = ((const uint4*)WpH)[k * 64 + it];
  }
  for (int idx = tid; idx < 2048; idx += 384) {
    int row = idx >> 6, c4 = idx & 63;
    int i = i0 + row;
    int b = i >> 8, t = i & 255;
    int dd = c4 >> 5, cc = c4 & 31;
    const uint4* hpg = (const uint4*)(H + (((size_t)dd * NB + b) * NT + t) * 256);
    hbuf[row][c4] = hpg[cc];
  }
  __syncthreads();
  int row = tid / 12, k = tid - row * 12;
  float s0 = 0.f, s1 = 0.f, s2 = 0.f, s3 = 0.f;
#pragma unroll 8
  for (int it = 0; it < 64; ++it) {
    uint4 h4 = hbuf[row][it];
    uint4 w4 = wbuf[it][k];
    s0 = dot2h(h4.x, w4.x, s0); s1 = dot2h(h4.y, w4.y, s1);
    s2 = dot2h(h4.z, w4.z, s2); s3 = dot2h(h4.w, w4.w, s3);
  }
  int i = i0 + row;
  FT[(size_t)i * NKTAG + k] = (s0 + s1) + (s2 + s3) + bp[k];
}

// ---------------------------------------------------------------- viterbi
// (unchanged from round 13, incl. FT prefetch)
__global__ __launch_bounds__(64) void viterbi_kernel(const float* __restrict__ FT,
                                                     const float* __restrict__ trans,
                                                     const int* __restrict__ sent,
                                                     float* __restrict__ out) {
  int b = blockIdx.x, tid = threadIdx.x;
  __shared__ float trans_s[12][12];
  __shared__ float s_s[12];
  __shared__ unsigned char bp_s[256][12];
  __shared__ int path_s[256];
  for (int idx = tid; idx < 144; idx += 64) trans_s[idx / 12][idx % 12] = trans[idx];
  int cnt = 0;
#pragma unroll
  for (int q = 0; q < 4; ++q) cnt += (sent[b * NT + q * 64 + tid] > 0) ? 1 : 0;
  for (int off = 32; off; off >>= 1) cnt += __shfl_down(cnt, off);
  int len = __shfl(cnt, 0);
  if (tid < 12) s_s[tid] = (tid == START_TAG) ? 0.f : -10000.f;
  float f_next = (tid < 12) ? FT[((size_t)b * NT) * NKTAG + tid] : 0.f;
  __syncthreads();
  for (int t = 0; t < NT; ++t) {
    float best = 0.f, f = f_next;
    int barg = 0;
    if (t + 1 < NT && tid < 12)
      f_next = FT[((size_t)b * NT + t + 1) * NKTAG + tid];  // prefetch, state-indep
    if (tid < 12) {
      best = s_s[0] + trans_s[tid][0];
      barg = 0;
#pragma unroll
      for (int fr = 1; fr < 12; ++fr) {
        float v = s_s[fr] + trans_s[tid][fr];
        if (v > best) { best = v; barg = fr; }  // strict > keeps first (jnp.argmax)
      }
    }
    __syncthreads();
    if (tid < 12) {
      s_s[tid] = best + f;
      bp_s[t][tid] = (unsigned char)barg;
    }
    __syncthreads();
  }
  if (tid == 0) {
    float bs = s_s[0];
    int bt = 0;
    for (int k = 1; k < 12; ++k)
      if (s_s[k] > bs) { bs = s_s[k]; bt = k; }
    out[NB * NT + b] = bs;
    int x = bt;
    for (int tt = NT - 1; tt >= 0; --tt) {
      path_s[tt] = x;
      int nxt = bp_s[tt][x];
      if (tt < len) x = nxt;
    }
  }
  __syncthreads();
#pragma unroll
  for (int q = 0; q < 4; ++q) {
    int t = q * 64 + tid;
    out[b * NT + t] = (t < len) ? (float)path_s[t] : -1.0f;
  }
}

// ---------------------------------------------------------------- launch
extern "C" void kernel_launch(void* const* d_in, const int* in_sizes, int n_in,
                              void* d_out, int out_size, void* d_ws, size_t ws_size,
                              hipStream_t stream) {
  (void)in_sizes; (void)n_in; (void)out_size; (void)ws_size;
  const int*   sent  = (const int*)d_in[0];
  const float* emb   = (const float*)d_in[2];
  const float* Wih_f = (const float*)d_in[3];
  const float* Whh_f = (const float*)d_in[4];
  const float* bih_f = (const float*)d_in[5];
  const float* bhh_f = (const float*)d_in[6];
  const float* Wih_b = (const float*)d_in[7];
  const float* Whh_b = (const float*)d_in[8];
  const float* bih_b = (const float*)d_in[9];
  const float* bhh_b = (const float*)d_in[10];
  const float* Wp    = (const float*)d_in[11];
  const float* bp    = (const float*)d_in[12];
  const float* trans = (const float*)d_in[13];
  const float* h0    = (const float*)d_in[14];
  const float* c0    = (const float*)d_in[15];
  float* out = (float*)d_out;

  char* w = (char*)d_ws;
  u16*   X4  = (u16*)w;                                      // 67108864 B
  uint4* WTH = (uint4*)(w + 67108864);                       //  1048576 B
  float* FT  = (float*)(w + 68157440);                       //   786432 B
  unsigned int* WpH = (unsigned int*)(w + 68943872);         //    12288 B
  u16*   H   = (u16*)(w + 68956160);                         // 16777216 B

  pack_whh<<<dim3(257), dim3(256), 0, stream>>>(Whh_f, Whh_b, Wp, WTH, WpH);
  gemm_x<<<dim3(32, 128), dim3(256), 0, stream>>>(sent, emb, Wih_f, Wih_b,
                                                  bih_f, bhh_f, bih_b, bhh_b, X4);
  lstm_scan<<<dim3(128), dim3(512), 0, stream>>>(WTH, (const ushort4*)X4, h0, c0, H);
  feats_kernel<<<dim3(512), dim3(384), 0, stream>>>(H, WpH, bp, FT);
  viterbi_kernel<<<dim3(64), dim3(64), 0, stream>>>(FT, trans, sent, out);
}